// Round 7
// baseline (309.464 us; speedup 1.0000x reference)
//
#include <hip/hip_runtime.h>

typedef unsigned int uint;
typedef unsigned short ushort;

#define EPS 1e-5f
#define SLOPE 0.01f
#define GATHER_BLOCKS 2048
#define PK 136   // padded k-stride (bf16 elems) for LDS W^T

static inline int cdiv(long a, int b) { return (int)((a + b - 1) / b); }

typedef __attribute__((ext_vector_type(8))) short short8;
typedef __attribute__((ext_vector_type(4))) float f32x4;

__device__ inline float bf_lo(uint v) { return __uint_as_float(v << 16); }
__device__ inline float bf_hi(uint v) { return __uint_as_float(v & 0xffff0000u); }
__device__ inline ushort f2bf(float f) {
  uint u = __float_as_uint(f);
  u += 0x7fffu + ((u >> 16) & 1u);   // RNE
  return (ushort)(u >> 16);
}
__device__ inline uint pack2bf(float a, float b) {
  return (uint)f2bf(a) | ((uint)f2bf(b) << 16);
}

// ---------- degree ----------
__global__ void deg_kernel(const int* __restrict__ dst, int* __restrict__ degi, int E) {
  int e = blockIdx.x * 256 + threadIdx.x;
  if (e < E) atomicAdd(&degi[dst[e]], 1);
}

// ---------- block sums (+ dinv fused) ----------
__global__ __launch_bounds__(256) void bsum_kernel(const int* __restrict__ degi,
    int* __restrict__ bsum, float* __restrict__ dinv, int n) {
  int tid = threadIdx.x;
  int i = blockIdx.x * 256 + tid;
  int v = (i < n) ? degi[i] : 0;
  if (i < n) dinv[i] = rsqrtf((float)(v + 1));  // +1 self-loop
  int r = v;
  #pragma unroll
  for (int ofs = 32; ofs; ofs >>= 1) r += __shfl_down(r, ofs, 64);
  __shared__ int ws[4];
  if ((tid & 63) == 0) ws[tid >> 6] = r;
  __syncthreads();
  if (tid == 0) bsum[blockIdx.x] = ws[0] + ws[1] + ws[2] + ws[3];
}

__global__ __launch_bounds__(256) void bscan_kernel(const int* __restrict__ bsum,
    int* __restrict__ bofs, int* __restrict__ ptr_end, int nb) {
  int tid = threadIdx.x, lane = tid & 63, wv = tid >> 6;
  __shared__ int wsum[4];
  __shared__ int carry_s, tot_s;
  if (tid == 0) carry_s = 0;
  __syncthreads();
  for (int base = 0; base < nb; base += 256) {
    int i = base + tid;
    int v = (i < nb) ? bsum[i] : 0;
    int inc = v;
    #pragma unroll
    for (int ofs = 1; ofs < 64; ofs <<= 1) {
      int t = __shfl_up(inc, ofs, 64);
      if (lane >= ofs) inc += t;
    }
    if (lane == 63) wsum[wv] = inc;
    __syncthreads();
    if (tid == 0) {
      int a = carry_s;
      for (int w = 0; w < 4; ++w) { int t = wsum[w]; wsum[w] = a; a += t; }
      tot_s = a;
    }
    __syncthreads();
    if (i < nb) bofs[i] = wsum[wv] + inc - v;
    __syncthreads();
    if (tid == 0) carry_s = tot_s;
    __syncthreads();
  }
  if (tid == 0) *ptr_end = carry_s;
}

__global__ __launch_bounds__(256) void ptr_kernel(const int* __restrict__ degi,
    const int* __restrict__ bofs, int* __restrict__ ptr, int n) {
  int tid = threadIdx.x, lane = tid & 63, wv = tid >> 6;
  int i = blockIdx.x * 256 + tid;
  int v = (i < n) ? degi[i] : 0;
  int inc = v;
  #pragma unroll
  for (int ofs = 1; ofs < 64; ofs <<= 1) {
    int t = __shfl_up(inc, ofs, 64);
    if (lane >= ofs) inc += t;
  }
  __shared__ int wsum[4], woff[4];
  if (lane == 63) wsum[wv] = inc;
  __syncthreads();
  if (tid == 0) {
    int a = 0;
    for (int w = 0; w < 4; ++w) { woff[w] = a; a += wsum[w]; }
  }
  __syncthreads();
  if (i < n) ptr[i] = bofs[blockIdx.x] + woff[wv] + inc - v;
}

// ---------- CSR fill: packed u16 src | bf16 coeff ----------
__global__ void fill_kernel(const int* __restrict__ src, const int* __restrict__ dst,
    const float* __restrict__ dinv, const int* __restrict__ ptr,
    int* __restrict__ fillc, uint* __restrict__ csr, int E) {
  int e = blockIdx.x * 256 + threadIdx.x;
  if (e >= E) return;
  int s = src[e], d = dst[e];
  int pos = ptr[d] + atomicAdd(&fillc[d], 1);
  float c = dinv[s] * dinv[d];
  csr[pos] = (uint)s | ((uint)f2bf(c) << 16);
}

// ---------- MFMA GEMM: C_bf16[n][128] = A[n][128] @ W[128][128] ----------
template<bool FUSED, bool WRITEX, bool TWOW, bool XRESBF>
__global__ __launch_bounds__(256) void mfma_gemm(
    const float* __restrict__ Af, const uint* __restrict__ Az,
    const float* __restrict__ scale, const float* __restrict__ shift,
    const float* __restrict__ xresf, const uint* __restrict__ xresb,
    uint* __restrict__ xoutb,
    const float* __restrict__ W0, const float* __restrict__ W1,
    ushort* __restrict__ Cbf, int n) {
  __shared__ ushort sWt[128 * PK];
  const int tid = threadIdx.x;
  for (int t = tid; t < 1024; t += 256) {
    const int tk = t & 31;
    const int tc = t >> 5;
    float4 r0, r1, r2, r3;
    if (TWOW) {
      int c = tc * 4;
      const float* Wb = (c < 64) ? W0 : W1;
      int cc = (c < 64) ? c : c - 64;
      r0 = *(const float4*)&Wb[(tk * 4 + 0) * 64 + cc];
      r1 = *(const float4*)&Wb[(tk * 4 + 1) * 64 + cc];
      r2 = *(const float4*)&Wb[(tk * 4 + 2) * 64 + cc];
      r3 = *(const float4*)&Wb[(tk * 4 + 3) * 64 + cc];
    } else {
      r0 = *(const float4*)&W0[(tk * 4 + 0) * 128 + tc * 4];
      r1 = *(const float4*)&W0[(tk * 4 + 1) * 128 + tc * 4];
      r2 = *(const float4*)&W0[(tk * 4 + 2) * 128 + tc * 4];
      r3 = *(const float4*)&W0[(tk * 4 + 3) * 128 + tc * 4];
    }
    const float* p0 = (const float*)&r0;
    const float* p1 = (const float*)&r1;
    const float* p2 = (const float*)&r2;
    const float* p3 = (const float*)&r3;
    #pragma unroll
    for (int j = 0; j < 4; ++j) {
      uint lo = (uint)f2bf(p0[j]) | ((uint)f2bf(p1[j]) << 16);
      uint hi = (uint)f2bf(p2[j]) | ((uint)f2bf(p3[j]) << 16);
      *(uint2*)&sWt[(tc * 4 + j) * PK + tk * 4] = make_uint2(lo, hi);
    }
  }
  __syncthreads();

  const int w = tid >> 6;
  const int lane = tid & 63;
  const int l16 = lane & 15, q = lane >> 4;
  const int row0 = blockIdx.x * 128 + w * 32;

  f32x4 acc[2][8];
  #pragma unroll
  for (int mt = 0; mt < 2; ++mt)
    #pragma unroll
    for (int nt = 0; nt < 8; ++nt)
      acc[mt][nt] = (f32x4){0.f, 0.f, 0.f, 0.f};

  for (int ks = 0; ks < 4; ++ks) {
    const int kbase = ks * 32 + q * 8;
    short8 afrag[2];
    #pragma unroll
    for (int mt = 0; mt < 2; ++mt) {
      int row = row0 + mt * 16 + l16;
      float av[8] = {0.f,0.f,0.f,0.f,0.f,0.f,0.f,0.f};
      if (row < n) {
        if constexpr (FUSED) {
          uint4 zw = *(const uint4*)&Az[(size_t)row * 64 + (kbase >> 1)];
          float zv[8] = { bf_lo(zw.x), bf_hi(zw.x), bf_lo(zw.y), bf_hi(zw.y),
                          bf_lo(zw.z), bf_hi(zw.z), bf_lo(zw.w), bf_hi(zw.w) };
          float4 sc0 = *(const float4*)&scale[kbase];
          float4 sc1 = *(const float4*)&scale[kbase + 4];
          float4 sh0 = *(const float4*)&shift[kbase];
          float4 sh1 = *(const float4*)&shift[kbase + 4];
          float scv[8] = { sc0.x, sc0.y, sc0.z, sc0.w, sc1.x, sc1.y, sc1.z, sc1.w };
          float shv[8] = { sh0.x, sh0.y, sh0.z, sh0.w, sh1.x, sh1.y, sh1.z, sh1.w };
          float xv[8];
          if constexpr (XRESBF) {
            uint4 xw = *(const uint4*)&xresb[(size_t)row * 64 + (kbase >> 1)];
            xv[0]=bf_lo(xw.x); xv[1]=bf_hi(xw.x); xv[2]=bf_lo(xw.y); xv[3]=bf_hi(xw.y);
            xv[4]=bf_lo(xw.z); xv[5]=bf_hi(xw.z); xv[6]=bf_lo(xw.w); xv[7]=bf_hi(xw.w);
          } else {
            const float* Xr = xresf + (size_t)row * 128 + kbase;
            float4 x0 = *(const float4*)&Xr[0];
            float4 x1 = *(const float4*)&Xr[4];
            xv[0]=x0.x; xv[1]=x0.y; xv[2]=x0.z; xv[3]=x0.w;
            xv[4]=x1.x; xv[5]=x1.y; xv[6]=x1.z; xv[7]=x1.w;
          }
          #pragma unroll
          for (int j = 0; j < 8; ++j) {
            float u = fmaf(zv[j], scv[j], shv[j]);
            u = u >= 0.f ? u : SLOPE * u;
            av[j] = u + xv[j];
          }
          if constexpr (WRITEX) {
            uint4 o;
            o.x = pack2bf(av[0], av[1]); o.y = pack2bf(av[2], av[3]);
            o.z = pack2bf(av[4], av[5]); o.w = pack2bf(av[6], av[7]);
            *(uint4*)&xoutb[(size_t)row * 64 + (kbase >> 1)] = o;
          }
        } else {
          const float* Ar = Af + (size_t)row * 128 + kbase;
          float4 a0 = *(const float4*)&Ar[0];
          float4 a1 = *(const float4*)&Ar[4];
          av[0]=a0.x; av[1]=a0.y; av[2]=a0.z; av[3]=a0.w;
          av[4]=a1.x; av[5]=a1.y; av[6]=a1.z; av[7]=a1.w;
        }
      }
      short8 af;
      #pragma unroll
      for (int j = 0; j < 8; ++j) af[j] = (short)f2bf(av[j]);
      afrag[mt] = af;
    }
    #pragma unroll
    for (int nt = 0; nt < 8; ++nt) {
      short8 bfrag = *(const short8*)&sWt[(nt * 16 + l16) * PK + kbase];
      acc[0][nt] = __builtin_amdgcn_mfma_f32_16x16x32_bf16(afrag[0], bfrag, acc[0][nt], 0, 0, 0);
      acc[1][nt] = __builtin_amdgcn_mfma_f32_16x16x32_bf16(afrag[1], bfrag, acc[1][nt], 0, 0, 0);
    }
  }
  #pragma unroll
  for (int mt = 0; mt < 2; ++mt) {
    int rbase = row0 + mt * 16 + q * 4;
    #pragma unroll
    for (int nt = 0; nt < 8; ++nt) {
      int col = nt * 16 + l16;
      #pragma unroll
      for (int r = 0; r < 4; ++r) {
        int row = rbase + r;
        if (row < n) Cbf[(size_t)row * 128 + col] = f2bf(acc[mt][nt][r]);
      }
    }
  }
}

#define EDGE_FMA(E_, R_, AX_, AY_) { float c_ = bf_hi(E_); \
  AX_ = fmaf(c_, bf_lo(R_), AX_); AY_ = fmaf(c_, bf_hi(R_), AY_); }

// ---------- gather propagate + fused BN partial stats; 2 nodes per wave ----------
__global__ __launch_bounds__(256) void gather_layer(const int* __restrict__ ptr,
    const uint* __restrict__ csr, const uint* __restrict__ ybf,
    const float* __restrict__ b, const float* __restrict__ dinv,
    uint* __restrict__ zbf, float* __restrict__ psum, float* __restrict__ psq, int n) {
  const int tid = threadIdx.x;
  const int lane = tid & 63, wv = tid >> 6;
  float2 bb = *(const float2*)&b[lane * 2];
  float sx = 0.f, sy = 0.f, qx = 0.f, qy = 0.f;
  const int stride = gridDim.x * 8;
  for (int w = (blockIdx.x * 4 + wv) * 2; w < n; w += stride) {
    const bool has1 = (w + 1) < n;
    int p0 = ptr[w], p1 = ptr[w + 1];
    int p2 = has1 ? ptr[w + 2] : p1;
    float dv0 = dinv[w], c00 = dv0 * dv0;
    uint y0 = ybf[(size_t)w * 64 + lane];
    float a0x = fmaf(c00, bf_lo(y0), bb.x);
    float a0y = fmaf(c00, bf_hi(y0), bb.y);
    float a1x = 0.f, a1y = 0.f;
    if (has1) {
      float dv1 = dinv[w + 1], c01 = dv1 * dv1;
      uint y1 = ybf[(size_t)(w + 1) * 64 + lane];
      a1x = fmaf(c01, bf_lo(y1), bb.x);
      a1y = fmaf(c01, bf_hi(y1), bb.y);
    }
    int j0 = p0, j1 = p1;
    while (j0 + 4 <= p1 && j1 + 4 <= p2) {
      uint e0 = csr[j0], e1 = csr[j0+1], e2 = csr[j0+2], e3 = csr[j0+3];
      uint f0 = csr[j1], f1 = csr[j1+1], f2 = csr[j1+2], f3 = csr[j1+3];
      uint r0 = ybf[(size_t)(e0 & 0xffffu) * 64 + lane];
      uint r1 = ybf[(size_t)(e1 & 0xffffu) * 64 + lane];
      uint r2 = ybf[(size_t)(e2 & 0xffffu) * 64 + lane];
      uint r3 = ybf[(size_t)(e3 & 0xffffu) * 64 + lane];
      uint s0 = ybf[(size_t)(f0 & 0xffffu) * 64 + lane];
      uint s1 = ybf[(size_t)(f1 & 0xffffu) * 64 + lane];
      uint s2 = ybf[(size_t)(f2 & 0xffffu) * 64 + lane];
      uint s3 = ybf[(size_t)(f3 & 0xffffu) * 64 + lane];
      EDGE_FMA(e0, r0, a0x, a0y); EDGE_FMA(e1, r1, a0x, a0y);
      EDGE_FMA(e2, r2, a0x, a0y); EDGE_FMA(e3, r3, a0x, a0y);
      EDGE_FMA(f0, s0, a1x, a1y); EDGE_FMA(f1, s1, a1x, a1y);
      EDGE_FMA(f2, s2, a1x, a1y); EDGE_FMA(f3, s3, a1x, a1y);
      j0 += 4; j1 += 4;
    }
    while (j0 + 4 <= p1) {
      uint e0 = csr[j0], e1 = csr[j0+1], e2 = csr[j0+2], e3 = csr[j0+3];
      uint r0 = ybf[(size_t)(e0 & 0xffffu) * 64 + lane];
      uint r1 = ybf[(size_t)(e1 & 0xffffu) * 64 + lane];
      uint r2 = ybf[(size_t)(e2 & 0xffffu) * 64 + lane];
      uint r3 = ybf[(size_t)(e3 & 0xffffu) * 64 + lane];
      EDGE_FMA(e0, r0, a0x, a0y); EDGE_FMA(e1, r1, a0x, a0y);
      EDGE_FMA(e2, r2, a0x, a0y); EDGE_FMA(e3, r3, a0x, a0y);
      j0 += 4;
    }
    for (; j0 < p1; ++j0) {
      uint e = csr[j0];
      uint r = ybf[(size_t)(e & 0xffffu) * 64 + lane];
      EDGE_FMA(e, r, a0x, a0y);
    }
    while (j1 + 4 <= p2) {
      uint f0 = csr[j1], f1 = csr[j1+1], f2 = csr[j1+2], f3 = csr[j1+3];
      uint s0 = ybf[(size_t)(f0 & 0xffffu) * 64 + lane];
      uint s1 = ybf[(size_t)(f1 & 0xffffu) * 64 + lane];
      uint s2 = ybf[(size_t)(f2 & 0xffffu) * 64 + lane];
      uint s3 = ybf[(size_t)(f3 & 0xffffu) * 64 + lane];
      EDGE_FMA(f0, s0, a1x, a1y); EDGE_FMA(f1, s1, a1x, a1y);
      EDGE_FMA(f2, s2, a1x, a1y); EDGE_FMA(f3, s3, a1x, a1y);
      j1 += 4;
    }
    for (; j1 < p2; ++j1) {
      uint f = csr[j1];
      uint s = ybf[(size_t)(f & 0xffffu) * 64 + lane];
      EDGE_FMA(f, s, a1x, a1y);
    }
    zbf[(size_t)w * 64 + lane] = pack2bf(a0x, a0y);
    sx += a0x; sy += a0y;
    qx = fmaf(a0x, a0x, qx); qy = fmaf(a0y, a0y, qy);
    if (has1) {
      zbf[(size_t)(w + 1) * 64 + lane] = pack2bf(a1x, a1y);
      sx += a1x; sy += a1y;
      qx = fmaf(a1x, a1x, qx); qy = fmaf(a1y, a1y, qy);
    }
  }
  __shared__ float red[4][64];
  red[wv][lane] = sx; __syncthreads();
  if (wv == 0) psum[(size_t)blockIdx.x * 128 + lane * 2] =
      red[0][lane] + red[1][lane] + red[2][lane] + red[3][lane];
  __syncthreads();
  red[wv][lane] = sy; __syncthreads();
  if (wv == 0) psum[(size_t)blockIdx.x * 128 + lane * 2 + 1] =
      red[0][lane] + red[1][lane] + red[2][lane] + red[3][lane];
  __syncthreads();
  red[wv][lane] = qx; __syncthreads();
  if (wv == 0) psq[(size_t)blockIdx.x * 128 + lane * 2] =
      red[0][lane] + red[1][lane] + red[2][lane] + red[3][lane];
  __syncthreads();
  red[wv][lane] = qy; __syncthreads();
  if (wv == 0) psq[(size_t)blockIdx.x * 128 + lane * 2 + 1] =
      red[0][lane] + red[1][lane] + red[2][lane] + red[3][lane];
}

// ---------- heads gather: cols 0-63 -> mu, 64-127 -> logvar; 2 nodes per wave ----------
__global__ __launch_bounds__(256) void gather_heads(const int* __restrict__ ptr,
    const uint* __restrict__ csr, const uint* __restrict__ ybf,
    const float* __restrict__ bmu, const float* __restrict__ blv,
    const float* __restrict__ dinv, float* __restrict__ out, int n) {
  const int tid = threadIdx.x;
  const int lane = tid & 63, wv = tid >> 6;
  int col = lane * 2;
  const float* bias; size_t obase; int cc;
  if (col < 64) { obase = 0; bias = bmu; cc = col; }
  else { obase = (size_t)n * 64; bias = blv; cc = col - 64; }
  float bx = bias[cc], by = bias[cc + 1];
  const int stride = gridDim.x * 8;
  for (int w = (blockIdx.x * 4 + wv) * 2; w < n; w += stride) {
    const bool has1 = (w + 1) < n;
    int p0 = ptr[w], p1 = ptr[w + 1];
    int p2 = has1 ? ptr[w + 2] : p1;
    float dv0 = dinv[w], c00 = dv0 * dv0;
    uint y0 = ybf[(size_t)w * 64 + lane];
    float a0x = fmaf(c00, bf_lo(y0), bx);
    float a0y = fmaf(c00, bf_hi(y0), by);
    float a1x = 0.f, a1y = 0.f;
    if (has1) {
      float dv1 = dinv[w + 1], c01 = dv1 * dv1;
      uint y1 = ybf[(size_t)(w + 1) * 64 + lane];
      a1x = fmaf(c01, bf_lo(y1), bx);
      a1y = fmaf(c01, bf_hi(y1), by);
    }
    int j0 = p0, j1 = p1;
    while (j0 + 4 <= p1 && j1 + 4 <= p2) {
      uint e0 = csr[j0], e1 = csr[j0+1], e2 = csr[j0+2], e3 = csr[j0+3];
      uint f0 = csr[j1], f1 = csr[j1+1], f2 = csr[j1+2], f3 = csr[j1+3];
      uint r0 = ybf[(size_t)(e0 & 0xffffu) * 64 + lane];
      uint r1 = ybf[(size_t)(e1 & 0xffffu) * 64 + lane];
      uint r2 = ybf[(size_t)(e2 & 0xffffu) * 64 + lane];
      uint r3 = ybf[(size_t)(e3 & 0xffffu) * 64 + lane];
      uint s0 = ybf[(size_t)(f0 & 0xffffu) * 64 + lane];
      uint s1 = ybf[(size_t)(f1 & 0xffffu) * 64 + lane];
      uint s2 = ybf[(size_t)(f2 & 0xffffu) * 64 + lane];
      uint s3 = ybf[(size_t)(f3 & 0xffffu) * 64 + lane];
      EDGE_FMA(e0, r0, a0x, a0y); EDGE_FMA(e1, r1, a0x, a0y);
      EDGE_FMA(e2, r2, a0x, a0y); EDGE_FMA(e3, r3, a0x, a0y);
      EDGE_FMA(f0, s0, a1x, a1y); EDGE_FMA(f1, s1, a1x, a1y);
      EDGE_FMA(f2, s2, a1x, a1y); EDGE_FMA(f3, s3, a1x, a1y);
      j0 += 4; j1 += 4;
    }
    while (j0 + 4 <= p1) {
      uint e0 = csr[j0], e1 = csr[j0+1], e2 = csr[j0+2], e3 = csr[j0+3];
      uint r0 = ybf[(size_t)(e0 & 0xffffu) * 64 + lane];
      uint r1 = ybf[(size_t)(e1 & 0xffffu) * 64 + lane];
      uint r2 = ybf[(size_t)(e2 & 0xffffu) * 64 + lane];
      uint r3 = ybf[(size_t)(e3 & 0xffffu) * 64 + lane];
      EDGE_FMA(e0, r0, a0x, a0y); EDGE_FMA(e1, r1, a0x, a0y);
      EDGE_FMA(e2, r2, a0x, a0y); EDGE_FMA(e3, r3, a0x, a0y);
      j0 += 4;
    }
    for (; j0 < p1; ++j0) {
      uint e = csr[j0];
      uint r = ybf[(size_t)(e & 0xffffu) * 64 + lane];
      EDGE_FMA(e, r, a0x, a0y);
    }
    while (j1 + 4 <= p2) {
      uint f0 = csr[j1], f1 = csr[j1+1], f2 = csr[j1+2], f3 = csr[j1+3];
      uint s0 = ybf[(size_t)(f0 & 0xffffu) * 64 + lane];
      uint s1 = ybf[(size_t)(f1 & 0xffffu) * 64 + lane];
      uint s2 = ybf[(size_t)(f2 & 0xffffu) * 64 + lane];
      uint s3 = ybf[(size_t)(f3 & 0xffffu) * 64 + lane];
      EDGE_FMA(f0, s0, a1x, a1y); EDGE_FMA(f1, s1, a1x, a1y);
      EDGE_FMA(f2, s2, a1x, a1y); EDGE_FMA(f3, s3, a1x, a1y);
      j1 += 4;
    }
    for (; j1 < p2; ++j1) {
      uint f = csr[j1];
      uint s = ybf[(size_t)(f & 0xffffu) * 64 + lane];
      EDGE_FMA(f, s, a1x, a1y);
    }
    *(float2*)&out[obase + (size_t)w * 64 + cc] = make_float2(a0x, a0y);
    if (has1)
      *(float2*)&out[obase + (size_t)(w + 1) * 64 + cc] = make_float2(a1x, a1y);
  }
}

// ---------- BN finalize: 128 blocks (one per channel) ----------
__global__ __launch_bounds__(256) void bnfin_kernel(const float* __restrict__ psum,
    const float* __restrict__ psq, const float* __restrict__ gamma,
    const float* __restrict__ beta, float* __restrict__ scale,
    float* __restrict__ shift, int n, int nb) {
  const int c = blockIdx.x;
  const int tid = threadIdx.x;
  float s = 0.f, s2 = 0.f;
  for (int b = tid; b < nb; b += 256) {
    s += psum[(size_t)b * 128 + c];
    s2 += psq[(size_t)b * 128 + c];
  }
  #pragma unroll
  for (int ofs = 32; ofs; ofs >>= 1) {
    s += __shfl_down(s, ofs, 64);
    s2 += __shfl_down(s2, ofs, 64);
  }
  __shared__ float ws[4], wq[4];
  if ((tid & 63) == 0) { ws[tid >> 6] = s; wq[tid >> 6] = s2; }
  __syncthreads();
  if (tid == 0) {
    float S = ws[0] + ws[1] + ws[2] + ws[3];
    float Q = wq[0] + wq[1] + wq[2] + wq[3];
    float mean = S / (float)n;
    float var = Q / (float)n - mean * mean;
    float inv = rsqrtf(var + EPS);
    float sc = gamma[c] * inv;
    scale[c] = sc;
    shift[c] = beta[c] - mean * sc;
  }
}

extern "C" void kernel_launch(void* const* d_in, const int* in_sizes, int n_in,
                              void* d_out, int out_size, void* d_ws, size_t ws_size,
                              hipStream_t stream) {
  const float* x     = (const float*)d_in[0];
  const int*   ei    = (const int*)d_in[1];
  const float* Ws    = (const float*)d_in[2];
  const float* bs    = (const float*)d_in[3];
  const float* Wmu   = (const float*)d_in[4];
  const float* bmu   = (const float*)d_in[5];
  const float* Wlv   = (const float*)d_in[6];
  const float* blv   = (const float*)d_in[7];
  const float* gamma = (const float*)d_in[8];
  const float* beta  = (const float*)d_in[9];
  float* out = (float*)d_out;

  const int n = in_sizes[0] / 128;
  const int E = in_sizes[1] / 2;
  const int* srcI = ei;
  const int* dstI = ei + E;
  const int nb = cdiv(n, 256);

  char* wsp = (char*)d_ws;
  size_t off = 0;
  auto alloc = [&](size_t bytes) -> void* {
    void* p = wsp + off;
    off += (bytes + 255) & ~(size_t)255;
    return p;
  };
  int*    degi  = (int*)alloc((size_t)2 * n * 4);   // degi[n] + fillc[n] contiguous
  int*    fillc = degi + n;
  float*  dinv  = (float*)alloc((size_t)n * 4);
  int*    ptr   = (int*)alloc((size_t)(n + 1) * 4);
  int*    bsum  = (int*)alloc((size_t)nb * 4);
  int*    bofs  = (int*)alloc((size_t)nb * 4);
  uint*   csr   = (uint*)alloc((size_t)E * 4);
  ushort* ybf   = (ushort*)alloc((size_t)n * 128 * 2);
  uint*   zbf   = (uint*)alloc((size_t)n * 64 * 4);
  uint*   xbbf  = (uint*)alloc((size_t)n * 64 * 4);
  float*  psum  = (float*)alloc((size_t)GATHER_BLOCKS * 128 * 4);
  float*  psq   = (float*)alloc((size_t)GATHER_BLOCKS * 128 * 4);
  float*  scale = (float*)alloc(128 * 4);
  float*  shift = (float*)alloc(128 * 4);
  (void)n_in; (void)out_size; (void)ws_size;

  hipMemsetAsync(degi, 0, (size_t)2 * n * 4, stream);
  deg_kernel<<<cdiv(E, 256), 256, 0, stream>>>(dstI, degi, E);
  bsum_kernel<<<nb, 256, 0, stream>>>(degi, bsum, dinv, n);
  bscan_kernel<<<1, 256, 0, stream>>>(bsum, bofs, ptr + n, nb);
  ptr_kernel<<<nb, 256, 0, stream>>>(degi, bofs, ptr, n);
  fill_kernel<<<cdiv(E, 256), 256, 0, stream>>>(srcI, dstI, dinv, ptr, fillc, csr, E);

  const int ggrid = cdiv(n, 128);

  // layer 0
  mfma_gemm<false, false, false, false><<<ggrid, 256, 0, stream>>>(
      x, nullptr, nullptr, nullptr, nullptr, nullptr, nullptr, Ws, nullptr, ybf, n);
  gather_layer<<<GATHER_BLOCKS, 256, 0, stream>>>(ptr, csr, (const uint*)ybf, bs, dinv, zbf, psum, psq, n);
  bnfin_kernel<<<128, 256, 0, stream>>>(psum, psq, gamma, beta, scale, shift, n, GATHER_BLOCKS);
  // layer 1 (fused BN+leaky+res, xres = x f32, writes xbbf packed)
  mfma_gemm<true, true, false, false><<<ggrid, 256, 0, stream>>>(
      nullptr, zbf, scale, shift, x, nullptr, xbbf, Ws + 16384, nullptr, ybf, n);
  gather_layer<<<GATHER_BLOCKS, 256, 0, stream>>>(ptr, csr, (const uint*)ybf, bs + 128, dinv, zbf, psum, psq, n);
  bnfin_kernel<<<128, 256, 0, stream>>>(psum, psq, gamma, beta, scale, shift, n, GATHER_BLOCKS);
  // layer 2 (xres = xbbf bf16, in-place update)
  mfma_gemm<true, true, false, true><<<ggrid, 256, 0, stream>>>(
      nullptr, zbf, scale, shift, nullptr, xbbf, xbbf, Ws + 32768, nullptr, ybf, n);
  gather_layer<<<GATHER_BLOCKS, 256, 0, stream>>>(ptr, csr, (const uint*)ybf, bs + 256, dinv, zbf, psum, psq, n);
  bnfin_kernel<<<128, 256, 0, stream>>>(psum, psq, gamma, beta, scale, shift, n, GATHER_BLOCKS);
  // heads: one GEMM with W = [Wmu | Wlv], one gather writing both outputs
  mfma_gemm<true, false, true, true><<<ggrid, 256, 0, stream>>>(
      nullptr, zbf, scale, shift, nullptr, xbbf, nullptr, Wmu, Wlv, ybf, n);
  gather_heads<<<GATHER_BLOCKS, 256, 0, stream>>>(ptr, csr, (const uint*)ybf, bmu, blv, dinv, out, n);
}

// Round 8
// 263.238 us; speedup vs baseline: 1.1756x; 1.1756x over previous
//
#include <hip/hip_runtime.h>

typedef unsigned int uint;
typedef unsigned short ushort;

#define EPS 1e-5f
#define SLOPE 0.01f
#define GATHER_BLOCKS 2048
#define PK 136   // padded k-stride (bf16 elems) for LDS W^T

static inline int cdiv(long a, int b) { return (int)((a + b - 1) / b); }

typedef __attribute__((ext_vector_type(8))) short short8;
typedef __attribute__((ext_vector_type(4))) float f32x4;

__device__ inline float bf_lo(uint v) { return __uint_as_float(v << 16); }
__device__ inline float bf_hi(uint v) { return __uint_as_float(v & 0xffff0000u); }
__device__ inline ushort f2bf(float f) {
  uint u = __float_as_uint(f);
  u += 0x7fffu + ((u >> 16) & 1u);   // RNE
  return (ushort)(u >> 16);
}
__device__ inline uint pack2bf(float a, float b) {
  return (uint)f2bf(a) | ((uint)f2bf(b) << 16);
}

// ---------- degree ----------
__global__ void deg_kernel(const int* __restrict__ dst, int* __restrict__ degi, int E) {
  int e = blockIdx.x * 256 + threadIdx.x;
  if (e < E) atomicAdd(&degi[dst[e]], 1);
}

// ---------- block sums over PADDED degrees (+ dinv from raw) ----------
__global__ __launch_bounds__(256) void bsum_kernel(const int* __restrict__ degi,
    int* __restrict__ bsum, float* __restrict__ dinv, int n) {
  int tid = threadIdx.x;
  int i = blockIdx.x * 256 + tid;
  int v = (i < n) ? degi[i] : 0;
  if (i < n) dinv[i] = rsqrtf((float)(v + 1));  // +1 self-loop
  int r = (v + 3) & ~3;                         // padded degree
  #pragma unroll
  for (int ofs = 32; ofs; ofs >>= 1) r += __shfl_down(r, ofs, 64);
  __shared__ int ws[4];
  if ((tid & 63) == 0) ws[tid >> 6] = r;
  __syncthreads();
  if (tid == 0) bsum[blockIdx.x] = ws[0] + ws[1] + ws[2] + ws[3];
}

__global__ __launch_bounds__(256) void bscan_kernel(const int* __restrict__ bsum,
    int* __restrict__ bofs, int* __restrict__ ptr_end, int nb) {
  int tid = threadIdx.x, lane = tid & 63, wv = tid >> 6;
  __shared__ int wsum[4];
  __shared__ int carry_s, tot_s;
  if (tid == 0) carry_s = 0;
  __syncthreads();
  for (int base = 0; base < nb; base += 256) {
    int i = base + tid;
    int v = (i < nb) ? bsum[i] : 0;
    int inc = v;
    #pragma unroll
    for (int ofs = 1; ofs < 64; ofs <<= 1) {
      int t = __shfl_up(inc, ofs, 64);
      if (lane >= ofs) inc += t;
    }
    if (lane == 63) wsum[wv] = inc;
    __syncthreads();
    if (tid == 0) {
      int a = carry_s;
      for (int w = 0; w < 4; ++w) { int t = wsum[w]; wsum[w] = a; a += t; }
      tot_s = a;
    }
    __syncthreads();
    if (i < nb) bofs[i] = wsum[wv] + inc - v;
    __syncthreads();
    if (tid == 0) carry_s = tot_s;
    __syncthreads();
  }
  if (tid == 0) *ptr_end = carry_s;
}

__global__ __launch_bounds__(256) void ptr_kernel(const int* __restrict__ degi,
    const int* __restrict__ bofs, int* __restrict__ ptr, int n) {
  int tid = threadIdx.x, lane = tid & 63, wv = tid >> 6;
  int i = blockIdx.x * 256 + tid;
  int v = (i < n) ? ((degi[i] + 3) & ~3) : 0;   // padded degree
  int inc = v;
  #pragma unroll
  for (int ofs = 1; ofs < 64; ofs <<= 1) {
    int t = __shfl_up(inc, ofs, 64);
    if (lane >= ofs) inc += t;
  }
  __shared__ int wsum[4], woff[4];
  if (lane == 63) wsum[wv] = inc;
  __syncthreads();
  if (tid == 0) {
    int a = 0;
    for (int w = 0; w < 4; ++w) { woff[w] = a; a += wsum[w]; }
  }
  __syncthreads();
  if (i < n) ptr[i] = bofs[blockIdx.x] + woff[wv] + inc - v;
}

// ---------- CSR fill: packed u16 src | bf16 coeff (pad stays 0) ----------
__global__ void fill_kernel(const int* __restrict__ src, const int* __restrict__ dst,
    const float* __restrict__ dinv, const int* __restrict__ ptr,
    int* __restrict__ fillc, uint* __restrict__ csr, int E) {
  int e = blockIdx.x * 256 + threadIdx.x;
  if (e >= E) return;
  int s = src[e], d = dst[e];
  int pos = ptr[d] + atomicAdd(&fillc[d], 1);
  float c = dinv[s] * dinv[d];
  csr[pos] = (uint)s | ((uint)f2bf(c) << 16);
}

// ---------- MFMA GEMM: C_bf16[n][128] = A[n][128] @ W[128][128] ----------
template<bool FUSED, bool WRITEX, bool TWOW, bool XRESBF>
__global__ __launch_bounds__(256) void mfma_gemm(
    const float* __restrict__ Af, const uint* __restrict__ Az,
    const float* __restrict__ scale, const float* __restrict__ shift,
    const float* __restrict__ xresf, const uint* __restrict__ xresb,
    uint* __restrict__ xoutb,
    const float* __restrict__ W0, const float* __restrict__ W1,
    ushort* __restrict__ Cbf, int n) {
  __shared__ ushort sWt[128 * PK];
  const int tid = threadIdx.x;
  for (int t = tid; t < 1024; t += 256) {
    const int tk = t & 31;
    const int tc = t >> 5;
    float4 r0, r1, r2, r3;
    if (TWOW) {
      int c = tc * 4;
      const float* Wb = (c < 64) ? W0 : W1;
      int cc = (c < 64) ? c : c - 64;
      r0 = *(const float4*)&Wb[(tk * 4 + 0) * 64 + cc];
      r1 = *(const float4*)&Wb[(tk * 4 + 1) * 64 + cc];
      r2 = *(const float4*)&Wb[(tk * 4 + 2) * 64 + cc];
      r3 = *(const float4*)&Wb[(tk * 4 + 3) * 64 + cc];
    } else {
      r0 = *(const float4*)&W0[(tk * 4 + 0) * 128 + tc * 4];
      r1 = *(const float4*)&W0[(tk * 4 + 1) * 128 + tc * 4];
      r2 = *(const float4*)&W0[(tk * 4 + 2) * 128 + tc * 4];
      r3 = *(const float4*)&W0[(tk * 4 + 3) * 128 + tc * 4];
    }
    const float* p0 = (const float*)&r0;
    const float* p1 = (const float*)&r1;
    const float* p2 = (const float*)&r2;
    const float* p3 = (const float*)&r3;
    #pragma unroll
    for (int j = 0; j < 4; ++j) {
      uint lo = (uint)f2bf(p0[j]) | ((uint)f2bf(p1[j]) << 16);
      uint hi = (uint)f2bf(p2[j]) | ((uint)f2bf(p3[j]) << 16);
      *(uint2*)&sWt[(tc * 4 + j) * PK + tk * 4] = make_uint2(lo, hi);
    }
  }
  __syncthreads();

  const int w = tid >> 6;
  const int lane = tid & 63;
  const int l16 = lane & 15, q = lane >> 4;
  const int row0 = blockIdx.x * 128 + w * 32;

  f32x4 acc[2][8];
  #pragma unroll
  for (int mt = 0; mt < 2; ++mt)
    #pragma unroll
    for (int nt = 0; nt < 8; ++nt)
      acc[mt][nt] = (f32x4){0.f, 0.f, 0.f, 0.f};

  for (int ks = 0; ks < 4; ++ks) {
    const int kbase = ks * 32 + q * 8;
    short8 afrag[2];
    #pragma unroll
    for (int mt = 0; mt < 2; ++mt) {
      int row = row0 + mt * 16 + l16;
      float av[8] = {0.f,0.f,0.f,0.f,0.f,0.f,0.f,0.f};
      if (row < n) {
        if constexpr (FUSED) {
          uint4 zw = *(const uint4*)&Az[(size_t)row * 64 + (kbase >> 1)];
          float zv[8] = { bf_lo(zw.x), bf_hi(zw.x), bf_lo(zw.y), bf_hi(zw.y),
                          bf_lo(zw.z), bf_hi(zw.z), bf_lo(zw.w), bf_hi(zw.w) };
          float4 sc0 = *(const float4*)&scale[kbase];
          float4 sc1 = *(const float4*)&scale[kbase + 4];
          float4 sh0 = *(const float4*)&shift[kbase];
          float4 sh1 = *(const float4*)&shift[kbase + 4];
          float scv[8] = { sc0.x, sc0.y, sc0.z, sc0.w, sc1.x, sc1.y, sc1.z, sc1.w };
          float shv[8] = { sh0.x, sh0.y, sh0.z, sh0.w, sh1.x, sh1.y, sh1.z, sh1.w };
          float xv[8];
          if constexpr (XRESBF) {
            uint4 xw = *(const uint4*)&xresb[(size_t)row * 64 + (kbase >> 1)];
            xv[0]=bf_lo(xw.x); xv[1]=bf_hi(xw.x); xv[2]=bf_lo(xw.y); xv[3]=bf_hi(xw.y);
            xv[4]=bf_lo(xw.z); xv[5]=bf_hi(xw.z); xv[6]=bf_lo(xw.w); xv[7]=bf_hi(xw.w);
          } else {
            const float* Xr = xresf + (size_t)row * 128 + kbase;
            float4 x0 = *(const float4*)&Xr[0];
            float4 x1 = *(const float4*)&Xr[4];
            xv[0]=x0.x; xv[1]=x0.y; xv[2]=x0.z; xv[3]=x0.w;
            xv[4]=x1.x; xv[5]=x1.y; xv[6]=x1.z; xv[7]=x1.w;
          }
          #pragma unroll
          for (int j = 0; j < 8; ++j) {
            float u = fmaf(zv[j], scv[j], shv[j]);
            u = u >= 0.f ? u : SLOPE * u;
            av[j] = u + xv[j];
          }
          if constexpr (WRITEX) {
            uint4 o;
            o.x = pack2bf(av[0], av[1]); o.y = pack2bf(av[2], av[3]);
            o.z = pack2bf(av[4], av[5]); o.w = pack2bf(av[6], av[7]);
            *(uint4*)&xoutb[(size_t)row * 64 + (kbase >> 1)] = o;
          }
        } else {
          const float* Ar = Af + (size_t)row * 128 + kbase;
          float4 a0 = *(const float4*)&Ar[0];
          float4 a1 = *(const float4*)&Ar[4];
          av[0]=a0.x; av[1]=a0.y; av[2]=a0.z; av[3]=a0.w;
          av[4]=a1.x; av[5]=a1.y; av[6]=a1.z; av[7]=a1.w;
        }
      }
      short8 af;
      #pragma unroll
      for (int j = 0; j < 8; ++j) af[j] = (short)f2bf(av[j]);
      afrag[mt] = af;
    }
    #pragma unroll
    for (int nt = 0; nt < 8; ++nt) {
      short8 bfrag = *(const short8*)&sWt[(nt * 16 + l16) * PK + kbase];
      acc[0][nt] = __builtin_amdgcn_mfma_f32_16x16x32_bf16(afrag[0], bfrag, acc[0][nt], 0, 0, 0);
      acc[1][nt] = __builtin_amdgcn_mfma_f32_16x16x32_bf16(afrag[1], bfrag, acc[1][nt], 0, 0, 0);
    }
  }
  #pragma unroll
  for (int mt = 0; mt < 2; ++mt) {
    int rbase = row0 + mt * 16 + q * 4;
    #pragma unroll
    for (int nt = 0; nt < 8; ++nt) {
      int col = nt * 16 + l16;
      #pragma unroll
      for (int r = 0; r < 4; ++r) {
        int row = rbase + r;
        if (row < n) Cbf[(size_t)row * 128 + col] = f2bf(acc[mt][nt][r]);
      }
    }
  }
}

#define EDGE_FMA(E_, R_, AX_, AY_) { float c_ = bf_hi(E_); \
  AX_ = fmaf(c_, bf_lo(R_), AX_); AY_ = fmaf(c_, bf_hi(R_), AY_); }

// ---------- gather propagate + fused BN partial stats (padded CSR) ----------
__global__ __launch_bounds__(256) void gather_layer(const int* __restrict__ ptr,
    const uint* __restrict__ csr, const uint* __restrict__ ybf,
    const float* __restrict__ b, const float* __restrict__ dinv,
    uint* __restrict__ zbf, float* __restrict__ psum, float* __restrict__ psq, int n) {
  const int tid = threadIdx.x;
  const int lane = tid & 63, wv = tid >> 6;
  float2 bb = *(const float2*)&b[lane * 2];
  float sx = 0.f, sy = 0.f, qx = 0.f, qy = 0.f;
  const int wstride = gridDim.x * 4;
  for (int w = blockIdx.x * 4 + wv; w < n; w += wstride) {
    float dv = dinv[w], c0 = dv * dv;
    uint yv = ybf[(size_t)w * 64 + lane];
    float ax = fmaf(c0, bf_lo(yv), bb.x);
    float ay = fmaf(c0, bf_hi(yv), bb.y);
    int j = ptr[w], end = ptr[w + 1];     // end-j is a multiple of 4, 16B aligned
    while (j + 8 <= end) {
      uint4 ea = *(const uint4*)&csr[j];
      uint4 eb = *(const uint4*)&csr[j + 4];
      uint r0 = ybf[(size_t)(ea.x & 0xffffu) * 64 + lane];
      uint r1 = ybf[(size_t)(ea.y & 0xffffu) * 64 + lane];
      uint r2 = ybf[(size_t)(ea.z & 0xffffu) * 64 + lane];
      uint r3 = ybf[(size_t)(ea.w & 0xffffu) * 64 + lane];
      uint r4 = ybf[(size_t)(eb.x & 0xffffu) * 64 + lane];
      uint r5 = ybf[(size_t)(eb.y & 0xffffu) * 64 + lane];
      uint r6 = ybf[(size_t)(eb.z & 0xffffu) * 64 + lane];
      uint r7 = ybf[(size_t)(eb.w & 0xffffu) * 64 + lane];
      EDGE_FMA(ea.x, r0, ax, ay); EDGE_FMA(ea.y, r1, ax, ay);
      EDGE_FMA(ea.z, r2, ax, ay); EDGE_FMA(ea.w, r3, ax, ay);
      EDGE_FMA(eb.x, r4, ax, ay); EDGE_FMA(eb.y, r5, ax, ay);
      EDGE_FMA(eb.z, r6, ax, ay); EDGE_FMA(eb.w, r7, ax, ay);
      j += 8;
    }
    if (j < end) {                         // exactly 4 remain
      uint4 ea = *(const uint4*)&csr[j];
      uint r0 = ybf[(size_t)(ea.x & 0xffffu) * 64 + lane];
      uint r1 = ybf[(size_t)(ea.y & 0xffffu) * 64 + lane];
      uint r2 = ybf[(size_t)(ea.z & 0xffffu) * 64 + lane];
      uint r3 = ybf[(size_t)(ea.w & 0xffffu) * 64 + lane];
      EDGE_FMA(ea.x, r0, ax, ay); EDGE_FMA(ea.y, r1, ax, ay);
      EDGE_FMA(ea.z, r2, ax, ay); EDGE_FMA(ea.w, r3, ax, ay);
    }
    zbf[(size_t)w * 64 + lane] = pack2bf(ax, ay);
    sx += ax; sy += ay;
    qx = fmaf(ax, ax, qx); qy = fmaf(ay, ay, qy);
  }
  __shared__ float red[4][64];
  red[wv][lane] = sx; __syncthreads();
  if (wv == 0) psum[(size_t)blockIdx.x * 128 + lane * 2] =
      red[0][lane] + red[1][lane] + red[2][lane] + red[3][lane];
  __syncthreads();
  red[wv][lane] = sy; __syncthreads();
  if (wv == 0) psum[(size_t)blockIdx.x * 128 + lane * 2 + 1] =
      red[0][lane] + red[1][lane] + red[2][lane] + red[3][lane];
  __syncthreads();
  red[wv][lane] = qx; __syncthreads();
  if (wv == 0) psq[(size_t)blockIdx.x * 128 + lane * 2] =
      red[0][lane] + red[1][lane] + red[2][lane] + red[3][lane];
  __syncthreads();
  red[wv][lane] = qy; __syncthreads();
  if (wv == 0) psq[(size_t)blockIdx.x * 128 + lane * 2 + 1] =
      red[0][lane] + red[1][lane] + red[2][lane] + red[3][lane];
}

// ---------- heads gather: cols 0-63 -> mu, 64-127 -> logvar (padded CSR) ----------
__global__ __launch_bounds__(256) void gather_heads(const int* __restrict__ ptr,
    const uint* __restrict__ csr, const uint* __restrict__ ybf,
    const float* __restrict__ bmu, const float* __restrict__ blv,
    const float* __restrict__ dinv, float* __restrict__ out, int n) {
  const int tid = threadIdx.x;
  const int lane = tid & 63, wv = tid >> 6;
  int col = lane * 2;
  const float* bias; size_t obase; int cc;
  if (col < 64) { obase = 0; bias = bmu; cc = col; }
  else { obase = (size_t)n * 64; bias = blv; cc = col - 64; }
  float bx = bias[cc], by = bias[cc + 1];
  const int wstride = gridDim.x * 4;
  for (int w = blockIdx.x * 4 + wv; w < n; w += wstride) {
    float dv = dinv[w], c0 = dv * dv;
    uint yv = ybf[(size_t)w * 64 + lane];
    float ax = fmaf(c0, bf_lo(yv), bx);
    float ay = fmaf(c0, bf_hi(yv), by);
    int j = ptr[w], end = ptr[w + 1];
    while (j + 8 <= end) {
      uint4 ea = *(const uint4*)&csr[j];
      uint4 eb = *(const uint4*)&csr[j + 4];
      uint r0 = ybf[(size_t)(ea.x & 0xffffu) * 64 + lane];
      uint r1 = ybf[(size_t)(ea.y & 0xffffu) * 64 + lane];
      uint r2 = ybf[(size_t)(ea.z & 0xffffu) * 64 + lane];
      uint r3 = ybf[(size_t)(ea.w & 0xffffu) * 64 + lane];
      uint r4 = ybf[(size_t)(eb.x & 0xffffu) * 64 + lane];
      uint r5 = ybf[(size_t)(eb.y & 0xffffu) * 64 + lane];
      uint r6 = ybf[(size_t)(eb.z & 0xffffu) * 64 + lane];
      uint r7 = ybf[(size_t)(eb.w & 0xffffu) * 64 + lane];
      EDGE_FMA(ea.x, r0, ax, ay); EDGE_FMA(ea.y, r1, ax, ay);
      EDGE_FMA(ea.z, r2, ax, ay); EDGE_FMA(ea.w, r3, ax, ay);
      EDGE_FMA(eb.x, r4, ax, ay); EDGE_FMA(eb.y, r5, ax, ay);
      EDGE_FMA(eb.z, r6, ax, ay); EDGE_FMA(eb.w, r7, ax, ay);
      j += 8;
    }
    if (j < end) {
      uint4 ea = *(const uint4*)&csr[j];
      uint r0 = ybf[(size_t)(ea.x & 0xffffu) * 64 + lane];
      uint r1 = ybf[(size_t)(ea.y & 0xffffu) * 64 + lane];
      uint r2 = ybf[(size_t)(ea.z & 0xffffu) * 64 + lane];
      uint r3 = ybf[(size_t)(ea.w & 0xffffu) * 64 + lane];
      EDGE_FMA(ea.x, r0, ax, ay); EDGE_FMA(ea.y, r1, ax, ay);
      EDGE_FMA(ea.z, r2, ax, ay); EDGE_FMA(ea.w, r3, ax, ay);
    }
    *(float2*)&out[obase + (size_t)w * 64 + cc] = make_float2(ax, ay);
  }
}

// ---------- BN finalize: 128 blocks (one per channel) ----------
__global__ __launch_bounds__(256) void bnfin_kernel(const float* __restrict__ psum,
    const float* __restrict__ psq, const float* __restrict__ gamma,
    const float* __restrict__ beta, float* __restrict__ scale,
    float* __restrict__ shift, int n, int nb) {
  const int c = blockIdx.x;
  const int tid = threadIdx.x;
  float s = 0.f, s2 = 0.f;
  for (int b = tid; b < nb; b += 256) {
    s += psum[(size_t)b * 128 + c];
    s2 += psq[(size_t)b * 128 + c];
  }
  #pragma unroll
  for (int ofs = 32; ofs; ofs >>= 1) {
    s += __shfl_down(s, ofs, 64);
    s2 += __shfl_down(s2, ofs, 64);
  }
  __shared__ float ws[4], wq[4];
  if ((tid & 63) == 0) { ws[tid >> 6] = s; wq[tid >> 6] = s2; }
  __syncthreads();
  if (tid == 0) {
    float S = ws[0] + ws[1] + ws[2] + ws[3];
    float Q = wq[0] + wq[1] + wq[2] + wq[3];
    float mean = S / (float)n;
    float var = Q / (float)n - mean * mean;
    float inv = rsqrtf(var + EPS);
    float sc = gamma[c] * inv;
    scale[c] = sc;
    shift[c] = beta[c] - mean * sc;
  }
}

extern "C" void kernel_launch(void* const* d_in, const int* in_sizes, int n_in,
                              void* d_out, int out_size, void* d_ws, size_t ws_size,
                              hipStream_t stream) {
  const float* x     = (const float*)d_in[0];
  const int*   ei    = (const int*)d_in[1];
  const float* Ws    = (const float*)d_in[2];
  const float* bs    = (const float*)d_in[3];
  const float* Wmu   = (const float*)d_in[4];
  const float* bmu   = (const float*)d_in[5];
  const float* Wlv   = (const float*)d_in[6];
  const float* blv   = (const float*)d_in[7];
  const float* gamma = (const float*)d_in[8];
  const float* beta  = (const float*)d_in[9];
  float* out = (float*)d_out;

  const int n = in_sizes[0] / 128;
  const int E = in_sizes[1] / 2;
  const int* srcI = ei;
  const int* dstI = ei + E;
  const int nb = cdiv(n, 256);
  const size_t Epad = (size_t)E + 3 * (size_t)n;   // padded CSR capacity

  char* wsp = (char*)d_ws;
  size_t off = 0;
  auto alloc = [&](size_t bytes) -> void* {
    void* p = wsp + off;
    off += (bytes + 255) & ~(size_t)255;
    return p;
  };
  // contiguous zero region: degi[n] + fillc[n] + csr[Epad]
  int*    degi  = (int*)alloc(((size_t)2 * n + Epad) * 4);
  int*    fillc = degi + n;
  uint*   csr   = (uint*)(degi + 2 * n);
  float*  dinv  = (float*)alloc((size_t)n * 4);
  int*    ptr   = (int*)alloc((size_t)(n + 1) * 4);
  int*    bsum  = (int*)alloc((size_t)nb * 4);
  int*    bofs  = (int*)alloc((size_t)nb * 4);
  ushort* ybf   = (ushort*)alloc((size_t)n * 128 * 2);
  uint*   zbf   = (uint*)alloc((size_t)n * 64 * 4);
  uint*   xbbf  = (uint*)alloc((size_t)n * 64 * 4);
  float*  psum  = (float*)alloc((size_t)GATHER_BLOCKS * 128 * 4);
  float*  psq   = (float*)alloc((size_t)GATHER_BLOCKS * 128 * 4);
  float*  scale = (float*)alloc(128 * 4);
  float*  shift = (float*)alloc(128 * 4);
  (void)n_in; (void)out_size; (void)ws_size;

  hipMemsetAsync(degi, 0, ((size_t)2 * n + Epad) * 4, stream);
  deg_kernel<<<cdiv(E, 256), 256, 0, stream>>>(dstI, degi, E);
  bsum_kernel<<<nb, 256, 0, stream>>>(degi, bsum, dinv, n);
  bscan_kernel<<<1, 256, 0, stream>>>(bsum, bofs, ptr + n, nb);
  ptr_kernel<<<nb, 256, 0, stream>>>(degi, bofs, ptr, n);
  fill_kernel<<<cdiv(E, 256), 256, 0, stream>>>(srcI, dstI, dinv, ptr, fillc, csr, E);

  const int ggrid = cdiv(n, 128);

  // layer 0
  mfma_gemm<false, false, false, false><<<ggrid, 256, 0, stream>>>(
      x, nullptr, nullptr, nullptr, nullptr, nullptr, nullptr, Ws, nullptr, ybf, n);
  gather_layer<<<GATHER_BLOCKS, 256, 0, stream>>>(ptr, csr, (const uint*)ybf, bs, dinv, zbf, psum, psq, n);
  bnfin_kernel<<<128, 256, 0, stream>>>(psum, psq, gamma, beta, scale, shift, n, GATHER_BLOCKS);
  // layer 1 (fused BN+leaky+res, xres = x f32, writes xbbf packed)
  mfma_gemm<true, true, false, false><<<ggrid, 256, 0, stream>>>(
      nullptr, zbf, scale, shift, x, nullptr, xbbf, Ws + 16384, nullptr, ybf, n);
  gather_layer<<<GATHER_BLOCKS, 256, 0, stream>>>(ptr, csr, (const uint*)ybf, bs + 128, dinv, zbf, psum, psq, n);
  bnfin_kernel<<<128, 256, 0, stream>>>(psum, psq, gamma, beta, scale, shift, n, GATHER_BLOCKS);
  // layer 2 (xres = xbbf bf16, in-place update)
  mfma_gemm<true, true, false, true><<<ggrid, 256, 0, stream>>>(
      nullptr, zbf, scale, shift, nullptr, xbbf, xbbf, Ws + 32768, nullptr, ybf, n);
  gather_layer<<<GATHER_BLOCKS, 256, 0, stream>>>(ptr, csr, (const uint*)ybf, bs + 256, dinv, zbf, psum, psq, n);
  bnfin_kernel<<<128, 256, 0, stream>>>(psum, psq, gamma, beta, scale, shift, n, GATHER_BLOCKS);
  // heads: one GEMM with W = [Wmu | Wlv], one gather writing both outputs
  mfma_gemm<true, false, true, true><<<ggrid, 256, 0, stream>>>(
      nullptr, zbf, scale, shift, nullptr, xbbf, nullptr, Wmu, Wlv, ybf, n);
  gather_heads<<<GATHER_BLOCKS, 256, 0, stream>>>(ptr, csr, (const uint*)ybf, bmu, blv, dinv, out, n);
}